// Round 5
// baseline (670.801 us; speedup 1.0000x reference)
//
#include <hip/hip_runtime.h>
#include <math.h>

// NoisyTopKRouter: out0 = softmax over top-2 of (x @ route_w^T + route_b) scattered
// into [16384,64]; out1 = top-2 indices (as floats). noise inputs are dead.
//
// R5 vs R4:
//  - w-loads issued BEFORE stage(s+1) so in-order vmcnt retirement never forces
//    the x-prefetch to drain (R4 lost pipeline depth every seg -> VALUBusy 46%).
//  - KR=16 (compute 1024 cyc/seg > HBM latency), counted vmcnt(10)/vmcnt(2).
//  - LDS layout [i][g][c]: ds_read = base + compile-time imm, no per-read XOR;
//    4 token-groups are 64B apart -> 2-way bank aliasing (free per m136).
//  - red reduction two-round (8->4->1), aliased onto xstage: LDS = 32 KB total.

#define TOKENS 16384
#define EMB    4096
#define NE     64
#define TB     32                 // tokens per block
#define NWAVES 8
#define KQ     (EMB / NWAVES)     // 512 k per wave (split-K)
#define KR     16                 // k per segment
#define NSEG   (KQ / KR)          // 32

#define GLOAD_LDS16(g, l)                                                      \
    __builtin_amdgcn_global_load_lds(                                          \
        (const __attribute__((address_space(1))) void*)(g),                    \
        (__attribute__((address_space(3))) void*)(l), 16, 0, 0)

// wt4[k][le][m] = route_w[le + 16*m][k]  (1 MB in d_ws; lane le reads its 4
// experts {le, le+16, le+32, le+48} for one k as a single float4)
__global__ __launch_bounds__(256) void wt4_prep_kernel(const float* __restrict__ w,
                                                       float* __restrict__ wt4) {
    int idx = blockIdx.x * 256 + threadIdx.x;
    int k   = idx >> 6;
    int col = idx & 63;
    int le  = col >> 2;
    int m   = col & 3;
    wt4[idx] = w[(le + 16 * m) * EMB + k];
}

// 16 FMAs: token i, x scalar xc (one k), experts le+16*{0..3} via w4a[k]
#define FMA4(i, xc, k)                                                         \
    acc[i][0] = fmaf((xc), w4a[k].x, acc[i][0]);                               \
    acc[i][1] = fmaf((xc), w4a[k].y, acc[i][1]);                               \
    acc[i][2] = fmaf((xc), w4a[k].z, acc[i][2]);                               \
    acc[i][3] = fmaf((xc), w4a[k].w, acc[i][3]);

__global__ __launch_bounds__(512, 4) void router_kernel(const float* __restrict__ x,
                                                        const float* __restrict__ wt4,
                                                        const float* __restrict__ rb,
                                                        float* __restrict__ out) {
    __shared__ float smem[8192];   // 32 KB: xstage (8 waves x 2 bufs x 2KB) -> red

    const int tid  = threadIdx.x;
    const int lane = tid & 63;
    const int wq   = __builtin_amdgcn_readfirstlane(tid >> 6);
    const long tok0 = (long)blockIdx.x * TB;

    const int g  = lane >> 4;      // token group: tokens g*8..g*8+7
    const int le = lane & 15;      // expert lane: experts le + 16*m

    // staging source (LDS layout per buf: byte = i*256 + g*64 + c*16,
    // holding x[token g*8+i][k-chunk c] of the current 16-k segment)
    const int i_s = lane >> 4;
    const int g_s = (lane >> 2) & 3;
    const int c_s = lane & 3;
    const float* xs0 = x + (tok0 + g_s * 8 + i_s) * (long)EMB + wq * KQ + c_s * 4;
    const float* xs1 = xs0 + 4 * (long)EMB;    // i_s + 4

    const float* wp = wt4 + (long)(wq * KQ) * NE + le * 4;

    char* wb = (char*)smem + wq * 4096;        // wave LDS base (2 x 2KB bufs)
    const char* xb = wb + g * 64;              // per-lane read base

    float acc[8][4];
#pragma unroll
    for (int i = 0; i < 8; ++i)
#pragma unroll
        for (int m = 0; m < 4; ++m) acc[i][m] = 0.f;

    // prologue: stage seg 0 -> buf 0 (2 gload_lds outstanding)
    GLOAD_LDS16(xs0, wb);
    GLOAD_LDS16(xs1, wb + 1024);
    xs0 += KR; xs1 += KR;   // now point at seg 1

#define SEG_BODY(B, HAS_NEXT, WA_STR, WB_STR)                                  \
    {                                                                          \
        float4 w4a[16];                                                        \
        _Pragma("unroll")                                                      \
        for (int k = 0; k < 16; ++k)                                           \
            w4a[k] = *reinterpret_cast<const float4*>(wp + k * NE);            \
        __builtin_amdgcn_sched_barrier(0);                                     \
        if (HAS_NEXT) {                                                        \
            GLOAD_LDS16(xs0, wb + ((B) ^ 1) * 2048);                           \
            GLOAD_LDS16(xs1, wb + ((B) ^ 1) * 2048 + 1024);                    \
        }                                                                      \
        __builtin_amdgcn_sched_barrier(0);                                     \
        asm volatile("s_waitcnt vmcnt(" WA_STR ")" ::: "memory");              \
        __builtin_amdgcn_sched_barrier(0);                                     \
        _Pragma("unroll")                                                      \
        for (int c = 0; c < 2; ++c) {                                          \
            _Pragma("unroll")                                                  \
            for (int i = 0; i < 8; ++i) {                                      \
                const float4 xv = *reinterpret_cast<const float4*>(            \
                    xb + (B) * 2048 + i * 256 + c * 16);                       \
                FMA4(i, xv.x, c * 4 + 0)                                       \
                FMA4(i, xv.y, c * 4 + 1)                                       \
                FMA4(i, xv.z, c * 4 + 2)                                       \
                FMA4(i, xv.w, c * 4 + 3)                                       \
            }                                                                  \
        }                                                                      \
        asm volatile("s_waitcnt vmcnt(" WB_STR ")" ::: "memory");              \
        __builtin_amdgcn_sched_barrier(0);                                     \
        _Pragma("unroll")                                                      \
        for (int c = 2; c < 4; ++c) {                                          \
            _Pragma("unroll")                                                  \
            for (int i = 0; i < 8; ++i) {                                      \
                const float4 xv = *reinterpret_cast<const float4*>(            \
                    xb + (B) * 2048 + i * 256 + c * 16);                       \
                FMA4(i, xv.x, c * 4 + 0)                                       \
                FMA4(i, xv.y, c * 4 + 1)                                       \
                FMA4(i, xv.z, c * 4 + 2)                                       \
                FMA4(i, xv.w, c * 4 + 3)                                       \
            }                                                                  \
        }                                                                      \
        if (HAS_NEXT) { xs0 += KR; xs1 += KR; }                                \
        wp += KR * NE;                                                         \
    }

    // segs 0..29 (15 pairs), then 30 (stages 31), then peeled 31
    for (int s2 = 0; s2 < NSEG / 2 - 1; ++s2) {
        SEG_BODY(0, true, "10", "2")
        SEG_BODY(1, true, "10", "2")
    }
    SEG_BODY(0, true, "10", "2")     // s = 30
    SEG_BODY(1, false, "8", "0")     // s = 31 (no next stage)

#undef SEG_BODY

    // ---- two-round cross-wave reduction (aliases xstage; barrier-separated) ----
    __syncthreads();
    // round A: waves 4..7 store partials into red[(wq-4)][t][e]
    if (wq >= 4) {
#pragma unroll
        for (int i = 0; i < 8; ++i)
#pragma unroll
            for (int m = 0; m < 4; ++m)
                smem[((wq & 3) * 32 + g * 8 + i) * 64 + le + 16 * m] = acc[i][m];
    }
    __syncthreads();
    // round B: waves 0..3 accumulate into the same cells
    if (wq < 4) {
#pragma unroll
        for (int i = 0; i < 8; ++i)
#pragma unroll
            for (int m = 0; m < 4; ++m) {
                const int idx = ((wq & 3) * 32 + g * 8 + i) * 64 + le + 16 * m;
                smem[idx] += acc[i][m];
            }
    }
    __syncthreads();
    // final 4-way sum + bias -> smem[t*64+e] (each thread RMWs only its own cells)
    {
        const int t  = tid >> 4;          // 0..31
        const int e0 = (tid & 15) * 4;
        float4 sum = *reinterpret_cast<const float4*>(rb + e0);
#pragma unroll
        for (int r = 0; r < 4; ++r) {
            const float4 p = *reinterpret_cast<const float4*>(&smem[(r * 32 + t) * 64 + e0]);
            sum.x += p.x; sum.y += p.y; sum.z += p.z; sum.w += p.w;
        }
        *reinterpret_cast<float4*>(&smem[t * 64 + e0]) = sum;
    }
    __syncthreads();

    // top-2 (jax tie rule: ascending scan, strict >) + 2-way softmax
    if (tid < TB) {
        const int t = tid;
        float m1 = -INFINITY, m2 = -INFINITY;
        int i1 = 0, i2 = 0;
        for (int e = 0; e < NE; ++e) {
            float v = smem[t * 64 + e];
            if (v > m1)      { m2 = m1; i2 = i1; m1 = v; i1 = e; }
            else if (v > m2) { m2 = v;  i2 = e; }
        }
        const float ed = expf(m2 - m1);
        const float p1 = 1.f / (1.f + ed);
        smem[2048 + t]      = p1;
        smem[2048 + 32 + t] = 1.f - p1;
        smem[2048 + 64 + t] = (float)i1;
        smem[2048 + 96 + t] = (float)i2;
    }
    __syncthreads();

    // write router_output rows (every element, zeros included), float4 coalesced
    {
        const int t  = tid >> 4;
        const int e0 = (tid & 15) * 4;
        const int i1 = (int)smem[2048 + 64 + t];
        const int i2 = (int)smem[2048 + 96 + t];
        const float p1 = smem[2048 + t];
        const float p2 = smem[2048 + 32 + t];
        float v[4];
#pragma unroll
        for (int j = 0; j < 4; ++j) {
            const int e = e0 + j;
            v[j] = (e == i1) ? p1 : ((e == i2) ? p2 : 0.f);
        }
        *reinterpret_cast<float4*>(out + (tok0 + t) * NE + e0) =
            make_float4(v[0], v[1], v[2], v[3]);
    }
    if (tid < TB) {
        float* idxo = out + (long)TOKENS * NE + (tok0 + tid) * 2;
        idxo[0] = smem[2048 + 64 + tid];
        idxo[1] = smem[2048 + 96 + tid];
    }
}

extern "C" void kernel_launch(void* const* d_in, const int* in_sizes, int n_in,
                              void* d_out, int out_size, void* d_ws, size_t ws_size,
                              hipStream_t stream) {
    const float* x       = (const float*)d_in[0];
    const float* route_w = (const float*)d_in[2];
    const float* route_b = (const float*)d_in[3];
    float* wt4 = (float*)d_ws;          // 1 MB scratch
    float* out = (float*)d_out;

    hipLaunchKernelGGL(wt4_prep_kernel, dim3((EMB * NE) / 256), dim3(256), 0, stream,
                       route_w, wt4);
    hipLaunchKernelGGL(router_kernel, dim3(TOKENS / TB), dim3(512), 0, stream,
                       x, wt4, route_b, out);
}